// Round 18
// baseline (320.089 us; speedup 1.0000x reference)
//
#include <hip/hip_runtime.h>
#include <hip/hip_bf16.h>
#include <math.h>

#define FIN 128
#define HID 8
#define HEADS 8
#define C1 64     // HEADS*HID
#define CLS 40
#define NSLOPE 0.2f
#define NINF (-__builtin_inff())

typedef __hip_bfloat16 bf16;
typedef unsigned int uint32;
typedef int vint4 __attribute__((ext_vector_type(4)));   // native vec for nt loads

__device__ __forceinline__ float lrelu(float x) { return x >= 0.f ? x : NSLOPE * x; }
__device__ __forceinline__ vint4 ldnt4(const int* p) {
    return __builtin_nontemporal_load((const vint4*)p);
}
// exact bf16-pair decode: low half = even channel, high half = odd channel
__device__ __forceinline__ float bfLO(uint32 u) { return __uint_as_float(u << 16); }
__device__ __forceinline__ float bfHI(uint32 u) { return __uint_as_float(u & 0xffff0000u); }
__device__ __forceinline__ uint32 packbf(float a, float b) {
    union { bf16 h[2]; uint32 u; } p;
    p.h[0] = __float2bfloat16(a); p.h[1] = __float2bfloat16(b);
    return p.u;
}

// exclusive scan of (deg[i]+1): block-local
__global__ __launch_bounds__(256) void k_scan1(const int* __restrict__ deg,
    int* __restrict__ rowstart, int* __restrict__ bsum, int n) {
    __shared__ int sm[256];
    int t = threadIdx.x, i = blockIdx.x * 256 + t;
    int v = (i < n) ? deg[i] + 1 : 0;
    sm[t] = v; __syncthreads();
    int x = v;
    for (int off = 1; off < 256; off <<= 1) {
        int tv = (t >= off) ? sm[t - off] : 0;
        __syncthreads();
        x += tv; sm[t] = x; __syncthreads();
    }
    if (i < n) rowstart[i] = x - v;
    if (t == 255) bsum[blockIdx.x] = x;
}

__global__ __launch_bounds__(512) void k_scan2(int* __restrict__ bsum, int nb) {
    __shared__ int sm[512];
    int t = threadIdx.x;
    int v = (t < nb) ? bsum[t] : 0;
    sm[t] = v; __syncthreads();
    int x = v;
    for (int off = 1; off < 512; off <<= 1) {
        int tv = (t >= off) ? sm[t - off] : 0;
        __syncthreads();
        x += tv; sm[t] = x; __syncthreads();
    }
    if (t < nb) bsum[t] = x - v;
}

__global__ void k_scan3(int* __restrict__ rowstart, const int* __restrict__ bsum,
                        int n, int total) {
    int i = blockIdx.x * blockDim.x + threadIdx.x;
    if (i < n) rowstart[i] += bsum[i >> 8];
    if (i == 0) rowstart[n] = total;
}

// ---- XCD-sliced scatter + nt edge reads (rowstart becomes row END cursor) ----
__global__ __launch_bounds__(256) void k_scatter(const int* __restrict__ ei,
    int E, int En, int n, int* __restrict__ rowcur, int* __restrict__ csr) {
    int g = blockIdx.x & 7;
    int per8 = (n + 7) >> 3;
    int lo = g * per8, hi = min(n, lo + per8);
    int idx = (blockIdx.x >> 3) * 256 + threadIdx.x;   // int4 index
    int e0 = idx * 4;
    if (e0 + 3 < E) {
        vint4 dv = ldnt4(ei + E + e0);
        vint4 sv = ldnt4(ei + e0);
        if (dv.x >= lo && dv.x < hi) csr[atomicAdd(&rowcur[dv.x], 1)] = sv.x;
        if (dv.y >= lo && dv.y < hi) csr[atomicAdd(&rowcur[dv.y], 1)] = sv.y;
        if (dv.z >= lo && dv.z < hi) csr[atomicAdd(&rowcur[dv.z], 1)] = sv.z;
        if (dv.w >= lo && dv.w < hi) csr[atomicAdd(&rowcur[dv.w], 1)] = sv.w;
    } else {
        int e_end = min(e0 + 4, En);                   // own chunk only!
        for (int e = e0; e < e_end; ++e) {
            int s, d;
            if (e < E) { s = ei[e]; d = ei[E + e]; } else { s = d = e - E; }
            if (d >= lo && d < hi) csr[atomicAdd(&rowcur[d], 1)] = s;
        }
    }
}

// ---- gemm1 + FUSED LDS-histogram degree count (blocks 0..127, 8 slices x
//      16 chunks). Hist aliases BOTH dead GEMM tiles (50176 B >= 12500 ints)
//      -> stream amplification 16x -> 8x (51 MB, L3-served). ----
__global__ __launch_bounds__(256) void gemm1_kernel(
    const float* __restrict__ x, const float* __restrict__ W1,
    const float* __restrict__ a_src, const float* __restrict__ a_dst,
    bf16* __restrict__ h1b, float* __restrict__ alS, float* __restrict__ alD,
    int n, const int* __restrict__ ei, int E, int* __restrict__ deg) {
    __shared__ __align__(16) char smem_raw[50176];
    uint32 (*Wlu)[C1 / 2] = (uint32 (*)[C1 / 2])smem_raw;          // 16 KB
    float (*xs)[FIN + 4] = (float (*)[FIN + 4])(smem_raw + 16384); // 33.8 KB
    int t = threadIdx.x;
    const float4* W4 = (const float4*)W1;
    for (int i = t; i < FIN * (C1 / 4); i += 256) {
        float4 w = W4[i];
        int row = i / (C1 / 4), c4 = i % (C1 / 4);
        Wlu[row][c4 * 2]     = packbf(w.x, w.y);
        Wlu[row][c4 * 2 + 1] = packbf(w.z, w.w);
    }
    int node0 = blockIdx.x * 64;
    for (int i = t; i < 64 * (FIN / 4); i += 256) {
        int r = i / (FIN / 4), c = i % (FIN / 4);
        int nn = node0 + r;
        float4 v = {0.f, 0.f, 0.f, 0.f};
        if (nn < n) v = ((const float4*)x)[(size_t)nn * (FIN / 4) + c];
        *(float4*)&xs[r][c * 4] = v;
    }
    __syncthreads();
    int cg = t & 15, ng = t >> 4;
    int head = cg >> 1, hc = (cg & 1) * 4;
    float acc[4][4];
    #pragma unroll
    for (int i = 0; i < 4; ++i)
        for (int j = 0; j < 4; ++j) acc[i][j] = 0.f;
    #pragma unroll 2
    for (int k = 0; k < FIN; ++k) {
        uint2 wu = *(const uint2*)&Wlu[k][cg * 2];
        float w0 = bfLO(wu.x), w1 = bfHI(wu.x);
        float w2 = bfLO(wu.y), w3 = bfHI(wu.y);
        #pragma unroll
        for (int i = 0; i < 4; ++i) {
            float xv = xs[ng * 4 + i][k];
            acc[i][0] += xv * w0; acc[i][1] += xv * w1;
            acc[i][2] += xv * w2; acc[i][3] += xv * w3;
        }
    }
    float a_s[4], a_d[4];
    #pragma unroll
    for (int j = 0; j < 4; ++j) {
        a_s[j] = a_src[head * HID + hc + j];
        a_d[j] = a_dst[head * HID + hc + j];
    }
    #pragma unroll
    for (int i = 0; i < 4; ++i) {
        int node = node0 + ng * 4 + i;
        float as = acc[i][0] * a_s[0] + acc[i][1] * a_s[1]
                 + acc[i][2] * a_s[2] + acc[i][3] * a_s[3];
        float ad = acc[i][0] * a_d[0] + acc[i][1] * a_d[1]
                 + acc[i][2] * a_d[2] + acc[i][3] * a_d[3];
        as += __shfl_xor(as, 1, 64);
        ad += __shfl_xor(ad, 1, 64);
        if (node < n) {
            union { ushort4 u; bf16 b[4]; } pk;
            #pragma unroll
            for (int j = 0; j < 4; ++j) pk.b[j] = __float2bfloat16(acc[i][j]);
            ((ushort4*)h1b)[(size_t)node * (C1 / 4) + cg] = pk.u;
            if ((cg & 1) == 0) {
                alS[node * HEADS + head] = as;
                alD[node * HEADS + head] = ad;
            }
        }
    }
    // ---- fused degree: 128 blocks = 8 slices x 16 chunks, LDS histogram ----
    if (blockIdx.x < 128) {
        __syncthreads();                     // GEMM tiles dead
        int* hist = (int*)smem_raw;          // 12544 ints available
        int SLICE = (n + 7) >> 3;            // 12500 for n=100000
        int sl = blockIdx.x & 7;
        int lo = sl * SLICE, hi = min(n, lo + SLICE);
        int nbin = hi - lo;
        for (int i = t; i < nbin; i += 256) hist[i] = 0;
        __syncthreads();
        int nI4 = E >> 2;
        for (int idx = (blockIdx.x >> 3) * 256 + t; idx < nI4; idx += 4096) {
            vint4 dv = ldnt4(ei + E + idx * 4);
            if (dv.x >= lo && dv.x < hi) atomicAdd(&hist[dv.x - lo], 1);
            if (dv.y >= lo && dv.y < hi) atomicAdd(&hist[dv.y - lo], 1);
            if (dv.z >= lo && dv.z < hi) atomicAdd(&hist[dv.z - lo], 1);
            if (dv.w >= lo && dv.w < hi) atomicAdd(&hist[dv.w - lo], 1);
        }
        if (blockIdx.x == 0)                 // E%4 remainder, counted once
            for (int e = nI4 * 4 + t; e < E; e += 256) atomicAdd(&deg[ei[E + e]], 1);
        __syncthreads();
        for (int i = t; i < nbin; i += 256) {
            int v = hist[i];
            if (v) atomicAdd(&deg[lo + i], v);
        }
    }
}

// ---- layer 1 aggregate (two-phase, bf16-PAIR, 4-batch loads) + fused gemm2.
//      GOLDEN r10 hot loop — do not perturb. Grid-stride; W2 staged once/block. ----
__global__ __launch_bounds__(256) void k_agg1(
    const int* __restrict__ csr, const int* __restrict__ rowend,
    const int* __restrict__ deg,
    const float* __restrict__ alS, const float* __restrict__ alD,
    const bf16* __restrict__ h1b, const float* __restrict__ b1,
    const float* __restrict__ W2, const float* __restrict__ aS2,
    const float* __restrict__ aD2,
    bf16* __restrict__ h2b, float* __restrict__ alS2, float* __restrict__ alD2,
    int n) {
    __shared__ int    ls[4][64];
    __shared__ float4 lp4[4][128];          // p[edge][8 heads], 8.2 KB
    __shared__ float  xrow[4][64];          // 1 KB
    __shared__ float  Wl[C1][CLS];          // 10.2 KB
    int t = threadIdx.x;
    for (int i = t; i < C1 * CLS; i += 256) Wl[i / CLS][i % CLS] = W2[i];
    __syncthreads();
    int lane = t & 63, wv = t >> 6;
    int c32 = lane & 31;                    // channel-pair index (phase B)
    int par = lane >> 5;                    // edge parity (phase B)
    int hp  = c32 >> 2;                     // head of channel pair
    const float* lpf = (const float*)&lp4[wv][0];
    const uint32* h1u = (const uint32*)h1b; // row = 32 uints
    int stride = gridDim.x * 4;

    for (int d = blockIdx.x * 4 + wv; d < n; d += stride) {
        float4 ad0 = *(const float4*)(alD + d * HEADS);
        float4 ad1 = *(const float4*)(alD + d * HEADS + 4);
        float adh[8] = {ad0.x, ad0.y, ad0.z, ad0.w, ad1.x, ad1.y, ad1.z, ad1.w};
        int cnt  = deg[d] + 1;
        int base = rowend[d] - cnt;
        float accx = 0.f, accy = 0.f, den = 0.f;
        for (int jb = 0; jb < cnt; jb += 64) {
            int ec = min(64, cnt - jb);
            // phase A: one edge per lane, 8 exps once (all 64 lanes)
            int jj = jb + lane;
            bool on = jj < cnt;
            int s = on ? csr[base + jj] : 0;
            ls[wv][lane] = s;
            float4 a0 = *(const float4*)(alS + s * HEADS);
            float4 a1 = *(const float4*)(alS + s * HEADS + 4);
            float av[8] = {a0.x, a0.y, a0.z, a0.w, a1.x, a1.y, a1.z, a1.w};
            float pv[8];
            #pragma unroll
            for (int h = 0; h < 8; ++h)
                pv[h] = on ? __expf(lrelu(av[h] + adh[h])) : 0.f;
            lp4[wv][lane * 2]     = make_float4(pv[0], pv[1], pv[2], pv[3]);
            lp4[wv][lane * 2 + 1] = make_float4(pv[4], pv[5], pv[6], pv[7]);
            // phase B: half-wave per edge, lane = channel pair (zero-pad safe)
            int j = 0;
            for (; j + 8 <= ec; j += 8) {
                int j0 = j + par, j1 = j + 2 + par, j2 = j + 4 + par, j3 = j + 6 + par;
                int s0 = ls[wv][j0], s1 = ls[wv][j1];
                int s2 = ls[wv][j2], s3 = ls[wv][j3];
                float p0 = lpf[j0 * 8 + hp], p1 = lpf[j1 * 8 + hp];
                float p2 = lpf[j2 * 8 + hp], p3 = lpf[j3 * 8 + hp];
                uint32 u0 = h1u[s0 * 32 + c32], u1 = h1u[s1 * 32 + c32];
                uint32 u2 = h1u[s2 * 32 + c32], u3 = h1u[s3 * 32 + c32];
                accx = fmaf(p0, bfLO(u0), accx); accy = fmaf(p0, bfHI(u0), accy);
                accx = fmaf(p1, bfLO(u1), accx); accy = fmaf(p1, bfHI(u1), accy);
                accx = fmaf(p2, bfLO(u2), accx); accy = fmaf(p2, bfHI(u2), accy);
                accx = fmaf(p3, bfLO(u3), accx); accy = fmaf(p3, bfHI(u3), accy);
                den += p0 + p1 + p2 + p3;
            }
            for (; j < ec; j += 2) {
                int j0 = j + par;
                int s0 = ls[wv][j0];
                float p0 = lpf[j0 * 8 + hp];
                uint32 u0 = h1u[s0 * 32 + c32];
                accx = fmaf(p0, bfLO(u0), accx);
                accy = fmaf(p0, bfHI(u0), accy);
                den += p0;
            }
        }
        // combine the two parity streams
        accx += __shfl_xor(accx, 32, 64);
        accy += __shfl_xor(accy, 32, 64);
        den  += __shfl_xor(den, 32, 64);
        if (lane < 32) {
            float2 bb = *(const float2*)(b1 + 2 * c32);
            float vx = accx / den + bb.x;
            float vy = accy / den + bb.y;
            vx = vx > 0.f ? vx : 0.f;
            vy = vy > 0.f ? vy : 0.f;
            *(float2*)&xrow[wv][2 * c32] = make_float2(vx, vy);
        }
        // fused gemm2 (same-wave LDS; DS ops in-order, no barrier needed)
        bool act = lane < CLS;
        float h2c = 0.f;
        if (act) {
            #pragma unroll 8
            for (int k = 0; k < C1; ++k) h2c = fmaf(xrow[wv][k], Wl[k][lane], h2c);
        }
        float as2 = act ? h2c * aS2[lane] : 0.f;
        float ad2 = act ? h2c * aD2[lane] : 0.f;
        #pragma unroll
        for (int off = 1; off < 64; off <<= 1) {
            as2 += __shfl_xor(as2, off, 64);
            ad2 += __shfl_xor(ad2, off, 64);
        }
        if (act) h2b[d * CLS + lane] = __float2bfloat16(h2c);
        if (lane == 0) { alS2[d] = as2; alD2[d] = ad2; }
    }
}

// ---- layer 2 aggregate (two-phase, bf16-PAIR, 4-batch) + fused log_softmax.
//      GOLDEN r10 version — unchanged. ----
__global__ __launch_bounds__(256) void k_agg2(
    const int* __restrict__ csr, const int* __restrict__ rowend,
    const int* __restrict__ deg,
    const float* __restrict__ alS, const float* __restrict__ alD,
    const bf16* __restrict__ h2b, const float* __restrict__ b2,
    float* __restrict__ out, int n) {
    __shared__ int2 lsp[4][64];             // {src, p-bits}, 2 KB
    int lane = threadIdx.x & 63, wv = threadIdx.x >> 6;
    int d = blockIdx.x * 4 + wv;
    if (d >= n) return;                     // wave-uniform
    int c32 = lane & 31;                    // class-pair index
    int par = lane >> 5;                    // edge parity
    bool actB = c32 < (CLS / 2);            // 20 pairs per half
    const uint32* h2u = (const uint32*)h2b; // row = 20 uints
    float ad = alD[d];
    int cnt  = deg[d] + 1;
    int base = rowend[d] - cnt;
    float accx = 0.f, accy = 0.f, den = 0.f;
    for (int jb = 0; jb < cnt; jb += 64) {
        int ec = min(64, cnt - jb);
        // phase A: one edge per lane, ONE exp per edge
        int jj = jb + lane;
        bool on = jj < cnt;
        int s = on ? csr[base + jj] : 0;
        float p = on ? __expf(lrelu(alS[s] + ad)) : 0.f;
        den += p;
        lsp[wv][lane] = make_int2(s, __float_as_int(p));
        // phase B: half-wave per edge, loads batched before uses
        if (actB) {
            int j = 0;
            for (; j + 8 <= ec; j += 8) {
                int2 e0 = lsp[wv][j + par],     e1 = lsp[wv][j + 2 + par];
                int2 e2 = lsp[wv][j + 4 + par], e3 = lsp[wv][j + 6 + par];
                uint32 u0 = h2u[e0.x * 20 + c32], u1 = h2u[e1.x * 20 + c32];
                uint32 u2 = h2u[e2.x * 20 + c32], u3 = h2u[e3.x * 20 + c32];
                float p0 = __int_as_float(e0.y), p1 = __int_as_float(e1.y);
                float p2 = __int_as_float(e2.y), p3 = __int_as_float(e3.y);
                accx = fmaf(p0, bfLO(u0), accx); accy = fmaf(p0, bfHI(u0), accy);
                accx = fmaf(p1, bfLO(u1), accx); accy = fmaf(p1, bfHI(u1), accy);
                accx = fmaf(p2, bfLO(u2), accx); accy = fmaf(p2, bfHI(u2), accy);
                accx = fmaf(p3, bfLO(u3), accx); accy = fmaf(p3, bfHI(u3), accy);
            }
            for (; j < ec; j += 2) {
                int2 e0 = lsp[wv][j + par];
                uint32 u0 = h2u[e0.x * 20 + c32];
                float p0 = __int_as_float(e0.y);
                accx = fmaf(p0, bfLO(u0), accx);
                accy = fmaf(p0, bfHI(u0), accy);
            }
        }
    }
    // den: full-wave sum of per-lane partials
    #pragma unroll
    for (int off = 1; off < 64; off <<= 1) den += __shfl_xor(den, off, 64);
    // combine parity streams for the accumulators
    accx += __shfl_xor(accx, 32, 64);
    accy += __shfl_xor(accy, 32, 64);
    bool owner = (lane < 32) && actB;       // lane c32<20 holds classes 2c,2c+1
    float vx = 0.f, vy = 0.f;
    if (owner) {
        float2 bb = *(const float2*)(b2 + 2 * c32);
        vx = accx / den + bb.x;
        vy = accy / den + bb.y;
    }
    float mx = owner ? fmaxf(vx, vy) : NINF;
    #pragma unroll
    for (int off = 1; off < 64; off <<= 1) mx = fmaxf(mx, __shfl_xor(mx, off, 64));
    float sum = owner ? (__expf(vx - mx) + __expf(vy - mx)) : 0.f;
    #pragma unroll
    for (int off = 1; off < 64; off <<= 1) sum += __shfl_xor(sum, off, 64);
    float lse = mx + __logf(sum);
    if (owner)
        *(float2*)(out + (size_t)d * CLS + 2 * c32) = make_float2(vx - lse, vy - lse);
}

extern "C" void kernel_launch(void* const* d_in, const int* in_sizes, int n_in,
                              void* d_out, int out_size, void* d_ws, size_t ws_size,
                              hipStream_t stream) {
    const float* x   = (const float*)d_in[0];
    const int*   ei  = (const int*)d_in[1];
    const float* W1  = (const float*)d_in[2];
    const float* aS1 = (const float*)d_in[3];
    const float* aD1 = (const float*)d_in[4];
    const float* b1  = (const float*)d_in[5];
    const float* W2  = (const float*)d_in[6];
    const float* aS2 = (const float*)d_in[7];
    const float* aD2 = (const float*)d_in[8];
    const float* b2  = (const float*)d_in[9];
    float* out = (float*)d_out;

    int n = in_sizes[0] / FIN;   // 100000
    int E = in_sizes[1] / 2;     // 1600000
    int En = E + n;

    // ws layout (~36 MB): h1b bf16 n*64 | h2b bf16 n*40 | alS1 f32 n*8 |
    // alD1 f32 n*8 | alS2 f32 n | alD2 f32 n | csr int En | rowstart int n+1 |
    // deg int n | bsum int 512
    char* wsb = (char*)d_ws;
    bf16*  h1b  = (bf16*)wsb;
    bf16*  h2b  = h1b + (size_t)n * C1;
    float* alS1 = (float*)(h2b + (size_t)n * CLS);
    float* alD1 = alS1 + (size_t)n * HEADS;
    float* alS2 = alD1 + (size_t)n * HEADS;
    float* alD2 = alS2 + n;
    int*   csr  = (int*)(alD2 + n);
    int*   rowstart = csr + En;
    int*   deg  = rowstart + n + 1;
    int*   bsum = deg + n;

    const int T = 256;
    int nb = (n + 255) / 256;                      // 391 (<=512)
    int nblocks = (n + 63) / 64;
    if (nblocks < 128) nblocks = 128;              // deg tail needs 128 blocks

    // ---- gemm1 (+ fused LDS-histogram degree count) ----
    (void)hipMemsetAsync(deg, 0, (size_t)n * sizeof(int), stream);
    gemm1_kernel<<<nblocks, T, 0, stream>>>(x, W1, aS1, aD1, h1b, alS1, alD1,
                                            n, ei, E, deg);

    // ---- CSR build (scan + scatter) ----
    k_scan1<<<nb, T, 0, stream>>>(deg, rowstart, bsum, n);
    k_scan2<<<1, 512, 0, stream>>>(bsum, nb);
    k_scan3<<<nb, T, 0, stream>>>(rowstart, bsum, n, En);
    int chunks = (En + 1023) / 1024;               // 4 edges/thread
    k_scatter<<<chunks * 8, T, 0, stream>>>(ei, E, En, n, rowstart, csr);

    // ---- layer 1 aggregate (+ fused gemm2), grid-stride ----
    k_agg1<<<2048, T, 0, stream>>>(csr, rowstart, deg, alS1, alD1, h1b, b1,
                                   W2, aS2, aD2, h2b, alS2, alD2, n);

    // ---- layer 2 ----
    k_agg2<<<(n + 3) / 4, T, 0, stream>>>(csr, rowstart, deg, alS2, alD2, h2b, b2, out, n);
}

// Round 19
// 316.212 us; speedup vs baseline: 1.0123x; 1.0123x over previous
//
#include <hip/hip_runtime.h>
#include <hip/hip_bf16.h>
#include <math.h>

#define FIN 128
#define HID 8
#define HEADS 8
#define C1 64     // HEADS*HID
#define CLS 40
#define NSLOPE 0.2f
#define NINF (-__builtin_inff())

typedef __hip_bfloat16 bf16;
typedef unsigned int uint32;
typedef int vint4 __attribute__((ext_vector_type(4)));   // native vec for nt loads

__device__ __forceinline__ float lrelu(float x) { return x >= 0.f ? x : NSLOPE * x; }
__device__ __forceinline__ vint4 ldnt4(const int* p) {
    return __builtin_nontemporal_load((const vint4*)p);
}
// exact bf16-pair decode: low half = even channel, high half = odd channel
__device__ __forceinline__ float bfLO(uint32 u) { return __uint_as_float(u << 16); }
__device__ __forceinline__ float bfHI(uint32 u) { return __uint_as_float(u & 0xffff0000u); }
__device__ __forceinline__ uint32 packbf(float a, float b) {
    union { bf16 h[2]; uint32 u; } p;
    p.h[0] = __float2bfloat16(a); p.h[1] = __float2bfloat16(b);
    return p.u;
}

// exclusive scan of (deg[i]+1): block-local
__global__ __launch_bounds__(256) void k_scan1(const int* __restrict__ deg,
    int* __restrict__ rowstart, int* __restrict__ bsum, int n) {
    __shared__ int sm[256];
    int t = threadIdx.x, i = blockIdx.x * 256 + t;
    int v = (i < n) ? deg[i] + 1 : 0;
    sm[t] = v; __syncthreads();
    int x = v;
    for (int off = 1; off < 256; off <<= 1) {
        int tv = (t >= off) ? sm[t - off] : 0;
        __syncthreads();
        x += tv; sm[t] = x; __syncthreads();
    }
    if (i < n) rowstart[i] = x - v;
    if (t == 255) bsum[blockIdx.x] = x;
}

__global__ __launch_bounds__(512) void k_scan2(int* __restrict__ bsum, int nb) {
    __shared__ int sm[512];
    int t = threadIdx.x;
    int v = (t < nb) ? bsum[t] : 0;
    sm[t] = v; __syncthreads();
    int x = v;
    for (int off = 1; off < 512; off <<= 1) {
        int tv = (t >= off) ? sm[t - off] : 0;
        __syncthreads();
        x += tv; sm[t] = x; __syncthreads();
    }
    if (t < nb) bsum[t] = x - v;
}

__global__ void k_scan3(int* __restrict__ rowstart, const int* __restrict__ bsum,
                        int n, int total) {
    int i = blockIdx.x * blockDim.x + threadIdx.x;
    if (i < n) rowstart[i] += bsum[i >> 8];
    if (i == 0) rowstart[n] = total;
}

// ---- XCD-sliced scatter + nt edge reads (rowstart becomes row END cursor) ----
__global__ __launch_bounds__(256) void k_scatter(const int* __restrict__ ei,
    int E, int En, int n, int* __restrict__ rowcur, int* __restrict__ csr) {
    int g = blockIdx.x & 7;
    int per8 = (n + 7) >> 3;
    int lo = g * per8, hi = min(n, lo + per8);
    int idx = (blockIdx.x >> 3) * 256 + threadIdx.x;   // int4 index
    int e0 = idx * 4;
    if (e0 + 3 < E) {
        vint4 dv = ldnt4(ei + E + e0);
        vint4 sv = ldnt4(ei + e0);
        if (dv.x >= lo && dv.x < hi) csr[atomicAdd(&rowcur[dv.x], 1)] = sv.x;
        if (dv.y >= lo && dv.y < hi) csr[atomicAdd(&rowcur[dv.y], 1)] = sv.y;
        if (dv.z >= lo && dv.z < hi) csr[atomicAdd(&rowcur[dv.z], 1)] = sv.z;
        if (dv.w >= lo && dv.w < hi) csr[atomicAdd(&rowcur[dv.w], 1)] = sv.w;
    } else {
        int e_end = min(e0 + 4, En);                   // own chunk only!
        for (int e = e0; e < e_end; ++e) {
            int s, d;
            if (e < E) { s = ei[e]; d = ei[E + e]; } else { s = d = e - E; }
            if (d >= lo && d < hi) csr[atomicAdd(&rowcur[d], 1)] = s;
        }
    }
}

// ---- gemm1 + FUSED LDS-histogram degree count (blocks 0..255, 16 slices x
//      16 chunks). BOTH GEMM tiles bf16-packed -> 33.3 KB LDS -> 4-5 blocks/CU
//      (r18's 50 KB / 3-blocks was the GEMM's latency bottleneck). ----
__global__ __launch_bounds__(256) void gemm1_kernel(
    const float* __restrict__ x, const float* __restrict__ W1,
    const float* __restrict__ a_src, const float* __restrict__ a_dst,
    bf16* __restrict__ h1b, float* __restrict__ alS, float* __restrict__ alD,
    int n, const int* __restrict__ ei, int E, int* __restrict__ deg) {
    __shared__ __align__(16) char smem_raw[33280];
    uint32 (*Wlu)[C1 / 2] = (uint32 (*)[C1 / 2])smem_raw;            // 16 KB
    uint32 (*xsu)[FIN / 2 + 2] = (uint32 (*)[FIN / 2 + 2])(smem_raw + 16384); // 16.9 KB
    int t = threadIdx.x;
    const float4* W4 = (const float4*)W1;
    for (int i = t; i < FIN * (C1 / 4); i += 256) {
        float4 w = W4[i];
        int row = i / (C1 / 4), c4 = i % (C1 / 4);
        Wlu[row][c4 * 2]     = packbf(w.x, w.y);
        Wlu[row][c4 * 2 + 1] = packbf(w.z, w.w);
    }
    int node0 = blockIdx.x * 64;
    for (int i = t; i < 64 * (FIN / 4); i += 256) {
        int r = i / (FIN / 4), c = i % (FIN / 4);
        int nn = node0 + r;
        float4 v = {0.f, 0.f, 0.f, 0.f};
        if (nn < n) v = ((const float4*)x)[(size_t)nn * (FIN / 4) + c];
        xsu[r][c * 2]     = packbf(v.x, v.y);
        xsu[r][c * 2 + 1] = packbf(v.z, v.w);
    }
    __syncthreads();
    int cg = t & 15, ng = t >> 4;
    int head = cg >> 1, hc = (cg & 1) * 4;
    float acc[4][4];
    #pragma unroll
    for (int i = 0; i < 4; ++i)
        for (int j = 0; j < 4; ++j) acc[i][j] = 0.f;
    #pragma unroll 2
    for (int kp = 0; kp < FIN / 2; ++kp) {
        uint2 w0 = *(const uint2*)&Wlu[2 * kp][cg * 2];
        uint2 w1 = *(const uint2*)&Wlu[2 * kp + 1][cg * 2];
        float w00 = bfLO(w0.x), w01 = bfHI(w0.x), w02 = bfLO(w0.y), w03 = bfHI(w0.y);
        float w10 = bfLO(w1.x), w11 = bfHI(w1.x), w12 = bfLO(w1.y), w13 = bfHI(w1.y);
        #pragma unroll
        for (int i = 0; i < 4; ++i) {
            uint32 xu = xsu[ng * 4 + i][kp];
            float xlo = bfLO(xu), xhi = bfHI(xu);
            acc[i][0] = fmaf(xlo, w00, fmaf(xhi, w10, acc[i][0]));
            acc[i][1] = fmaf(xlo, w01, fmaf(xhi, w11, acc[i][1]));
            acc[i][2] = fmaf(xlo, w02, fmaf(xhi, w12, acc[i][2]));
            acc[i][3] = fmaf(xlo, w03, fmaf(xhi, w13, acc[i][3]));
        }
    }
    float a_s[4], a_d[4];
    #pragma unroll
    for (int j = 0; j < 4; ++j) {
        a_s[j] = a_src[head * HID + hc + j];
        a_d[j] = a_dst[head * HID + hc + j];
    }
    #pragma unroll
    for (int i = 0; i < 4; ++i) {
        int node = node0 + ng * 4 + i;
        float as = acc[i][0] * a_s[0] + acc[i][1] * a_s[1]
                 + acc[i][2] * a_s[2] + acc[i][3] * a_s[3];
        float ad = acc[i][0] * a_d[0] + acc[i][1] * a_d[1]
                 + acc[i][2] * a_d[2] + acc[i][3] * a_d[3];
        as += __shfl_xor(as, 1, 64);
        ad += __shfl_xor(ad, 1, 64);
        if (node < n) {
            union { ushort4 u; bf16 b[4]; } pk;
            #pragma unroll
            for (int j = 0; j < 4; ++j) pk.b[j] = __float2bfloat16(acc[i][j]);
            ((ushort4*)h1b)[(size_t)node * (C1 / 4) + cg] = pk.u;
            if ((cg & 1) == 0) {
                alS[node * HEADS + head] = as;
                alD[node * HEADS + head] = ad;
            }
        }
    }
    // ---- fused degree: 256 blocks = 16 slices x 16 chunks, LDS histogram ----
    if (blockIdx.x < 256) {
        __syncthreads();                     // GEMM tiles dead
        int* hist = (int*)smem_raw;          // 8320 ints available
        int SLICE = (n + 15) >> 4;           // 6250 for n=100000
        int sl = blockIdx.x & 15;
        int lo = sl * SLICE, hi = min(n, lo + SLICE);
        int nbin = hi - lo;
        for (int i = t; i < nbin; i += 256) hist[i] = 0;
        __syncthreads();
        int nI4 = E >> 2;
        for (int idx = (blockIdx.x >> 4) * 256 + t; idx < nI4; idx += 4096) {
            vint4 dv = ldnt4(ei + E + idx * 4);
            if (dv.x >= lo && dv.x < hi) atomicAdd(&hist[dv.x - lo], 1);
            if (dv.y >= lo && dv.y < hi) atomicAdd(&hist[dv.y - lo], 1);
            if (dv.z >= lo && dv.z < hi) atomicAdd(&hist[dv.z - lo], 1);
            if (dv.w >= lo && dv.w < hi) atomicAdd(&hist[dv.w - lo], 1);
        }
        if (blockIdx.x == 0)                 // E%4 remainder, counted once
            for (int e = nI4 * 4 + t; e < E; e += 256) atomicAdd(&deg[ei[E + e]], 1);
        __syncthreads();
        for (int i = t; i < nbin; i += 256) {
            int v = hist[i];
            if (v) atomicAdd(&deg[lo + i], v);
        }
    }
}

// ---- layer 1 aggregate (two-phase, bf16-PAIR, 4-batch loads) + fused gemm2.
//      GOLDEN r10 hot loop — do not perturb. Grid-stride; W2 staged once/block. ----
__global__ __launch_bounds__(256) void k_agg1(
    const int* __restrict__ csr, const int* __restrict__ rowend,
    const int* __restrict__ deg,
    const float* __restrict__ alS, const float* __restrict__ alD,
    const bf16* __restrict__ h1b, const float* __restrict__ b1,
    const float* __restrict__ W2, const float* __restrict__ aS2,
    const float* __restrict__ aD2,
    bf16* __restrict__ h2b, float* __restrict__ alS2, float* __restrict__ alD2,
    int n) {
    __shared__ int    ls[4][64];
    __shared__ float4 lp4[4][128];          // p[edge][8 heads], 8.2 KB
    __shared__ float  xrow[4][64];          // 1 KB
    __shared__ float  Wl[C1][CLS];          // 10.2 KB
    int t = threadIdx.x;
    for (int i = t; i < C1 * CLS; i += 256) Wl[i / CLS][i % CLS] = W2[i];
    __syncthreads();
    int lane = t & 63, wv = t >> 6;
    int c32 = lane & 31;                    // channel-pair index (phase B)
    int par = lane >> 5;                    // edge parity (phase B)
    int hp  = c32 >> 2;                     // head of channel pair
    const float* lpf = (const float*)&lp4[wv][0];
    const uint32* h1u = (const uint32*)h1b; // row = 32 uints
    int stride = gridDim.x * 4;

    for (int d = blockIdx.x * 4 + wv; d < n; d += stride) {
        float4 ad0 = *(const float4*)(alD + d * HEADS);
        float4 ad1 = *(const float4*)(alD + d * HEADS + 4);
        float adh[8] = {ad0.x, ad0.y, ad0.z, ad0.w, ad1.x, ad1.y, ad1.z, ad1.w};
        int cnt  = deg[d] + 1;
        int base = rowend[d] - cnt;
        float accx = 0.f, accy = 0.f, den = 0.f;
        for (int jb = 0; jb < cnt; jb += 64) {
            int ec = min(64, cnt - jb);
            // phase A: one edge per lane, 8 exps once (all 64 lanes)
            int jj = jb + lane;
            bool on = jj < cnt;
            int s = on ? csr[base + jj] : 0;
            ls[wv][lane] = s;
            float4 a0 = *(const float4*)(alS + s * HEADS);
            float4 a1 = *(const float4*)(alS + s * HEADS + 4);
            float av[8] = {a0.x, a0.y, a0.z, a0.w, a1.x, a1.y, a1.z, a1.w};
            float pv[8];
            #pragma unroll
            for (int h = 0; h < 8; ++h)
                pv[h] = on ? __expf(lrelu(av[h] + adh[h])) : 0.f;
            lp4[wv][lane * 2]     = make_float4(pv[0], pv[1], pv[2], pv[3]);
            lp4[wv][lane * 2 + 1] = make_float4(pv[4], pv[5], pv[6], pv[7]);
            // phase B: half-wave per edge, lane = channel pair (zero-pad safe)
            int j = 0;
            for (; j + 8 <= ec; j += 8) {
                int j0 = j + par, j1 = j + 2 + par, j2 = j + 4 + par, j3 = j + 6 + par;
                int s0 = ls[wv][j0], s1 = ls[wv][j1];
                int s2 = ls[wv][j2], s3 = ls[wv][j3];
                float p0 = lpf[j0 * 8 + hp], p1 = lpf[j1 * 8 + hp];
                float p2 = lpf[j2 * 8 + hp], p3 = lpf[j3 * 8 + hp];
                uint32 u0 = h1u[s0 * 32 + c32], u1 = h1u[s1 * 32 + c32];
                uint32 u2 = h1u[s2 * 32 + c32], u3 = h1u[s3 * 32 + c32];
                accx = fmaf(p0, bfLO(u0), accx); accy = fmaf(p0, bfHI(u0), accy);
                accx = fmaf(p1, bfLO(u1), accx); accy = fmaf(p1, bfHI(u1), accy);
                accx = fmaf(p2, bfLO(u2), accx); accy = fmaf(p2, bfHI(u2), accy);
                accx = fmaf(p3, bfLO(u3), accx); accy = fmaf(p3, bfHI(u3), accy);
                den += p0 + p1 + p2 + p3;
            }
            for (; j < ec; j += 2) {
                int j0 = j + par;
                int s0 = ls[wv][j0];
                float p0 = lpf[j0 * 8 + hp];
                uint32 u0 = h1u[s0 * 32 + c32];
                accx = fmaf(p0, bfLO(u0), accx);
                accy = fmaf(p0, bfHI(u0), accy);
                den += p0;
            }
        }
        // combine the two parity streams
        accx += __shfl_xor(accx, 32, 64);
        accy += __shfl_xor(accy, 32, 64);
        den  += __shfl_xor(den, 32, 64);
        if (lane < 32) {
            float2 bb = *(const float2*)(b1 + 2 * c32);
            float vx = accx / den + bb.x;
            float vy = accy / den + bb.y;
            vx = vx > 0.f ? vx : 0.f;
            vy = vy > 0.f ? vy : 0.f;
            *(float2*)&xrow[wv][2 * c32] = make_float2(vx, vy);
        }
        // fused gemm2 (same-wave LDS; DS ops in-order, no barrier needed)
        bool act = lane < CLS;
        float h2c = 0.f;
        if (act) {
            #pragma unroll 8
            for (int k = 0; k < C1; ++k) h2c = fmaf(xrow[wv][k], Wl[k][lane], h2c);
        }
        float as2 = act ? h2c * aS2[lane] : 0.f;
        float ad2 = act ? h2c * aD2[lane] : 0.f;
        #pragma unroll
        for (int off = 1; off < 64; off <<= 1) {
            as2 += __shfl_xor(as2, off, 64);
            ad2 += __shfl_xor(ad2, off, 64);
        }
        if (act) h2b[d * CLS + lane] = __float2bfloat16(h2c);
        if (lane == 0) { alS2[d] = as2; alD2[d] = ad2; }
    }
}

// ---- layer 2 aggregate (two-phase, bf16-PAIR, 4-batch) + fused log_softmax.
//      GOLDEN r10 version — unchanged. ----
__global__ __launch_bounds__(256) void k_agg2(
    const int* __restrict__ csr, const int* __restrict__ rowend,
    const int* __restrict__ deg,
    const float* __restrict__ alS, const float* __restrict__ alD,
    const bf16* __restrict__ h2b, const float* __restrict__ b2,
    float* __restrict__ out, int n) {
    __shared__ int2 lsp[4][64];             // {src, p-bits}, 2 KB
    int lane = threadIdx.x & 63, wv = threadIdx.x >> 6;
    int d = blockIdx.x * 4 + wv;
    if (d >= n) return;                     // wave-uniform
    int c32 = lane & 31;                    // class-pair index
    int par = lane >> 5;                    // edge parity
    bool actB = c32 < (CLS / 2);            // 20 pairs per half
    const uint32* h2u = (const uint32*)h2b; // row = 20 uints
    float ad = alD[d];
    int cnt  = deg[d] + 1;
    int base = rowend[d] - cnt;
    float accx = 0.f, accy = 0.f, den = 0.f;
    for (int jb = 0; jb < cnt; jb += 64) {
        int ec = min(64, cnt - jb);
        // phase A: one edge per lane, ONE exp per edge
        int jj = jb + lane;
        bool on = jj < cnt;
        int s = on ? csr[base + jj] : 0;
        float p = on ? __expf(lrelu(alS[s] + ad)) : 0.f;
        den += p;
        lsp[wv][lane] = make_int2(s, __float_as_int(p));
        // phase B: half-wave per edge, loads batched before uses
        if (actB) {
            int j = 0;
            for (; j + 8 <= ec; j += 8) {
                int2 e0 = lsp[wv][j + par],     e1 = lsp[wv][j + 2 + par];
                int2 e2 = lsp[wv][j + 4 + par], e3 = lsp[wv][j + 6 + par];
                uint32 u0 = h2u[e0.x * 20 + c32], u1 = h2u[e1.x * 20 + c32];
                uint32 u2 = h2u[e2.x * 20 + c32], u3 = h2u[e3.x * 20 + c32];
                float p0 = __int_as_float(e0.y), p1 = __int_as_float(e1.y);
                float p2 = __int_as_float(e2.y), p3 = __int_as_float(e3.y);
                accx = fmaf(p0, bfLO(u0), accx); accy = fmaf(p0, bfHI(u0), accy);
                accx = fmaf(p1, bfLO(u1), accx); accy = fmaf(p1, bfHI(u1), accy);
                accx = fmaf(p2, bfLO(u2), accx); accy = fmaf(p2, bfHI(u2), accy);
                accx = fmaf(p3, bfLO(u3), accx); accy = fmaf(p3, bfHI(u3), accy);
            }
            for (; j < ec; j += 2) {
                int2 e0 = lsp[wv][j + par];
                uint32 u0 = h2u[e0.x * 20 + c32];
                float p0 = __int_as_float(e0.y);
                accx = fmaf(p0, bfLO(u0), accx);
                accy = fmaf(p0, bfHI(u0), accy);
            }
        }
    }
    // den: full-wave sum of per-lane partials
    #pragma unroll
    for (int off = 1; off < 64; off <<= 1) den += __shfl_xor(den, off, 64);
    // combine parity streams for the accumulators
    accx += __shfl_xor(accx, 32, 64);
    accy += __shfl_xor(accy, 32, 64);
    bool owner = (lane < 32) && actB;       // lane c32<20 holds classes 2c,2c+1
    float vx = 0.f, vy = 0.f;
    if (owner) {
        float2 bb = *(const float2*)(b2 + 2 * c32);
        vx = accx / den + bb.x;
        vy = accy / den + bb.y;
    }
    float mx = owner ? fmaxf(vx, vy) : NINF;
    #pragma unroll
    for (int off = 1; off < 64; off <<= 1) mx = fmaxf(mx, __shfl_xor(mx, off, 64));
    float sum = owner ? (__expf(vx - mx) + __expf(vy - mx)) : 0.f;
    #pragma unroll
    for (int off = 1; off < 64; off <<= 1) sum += __shfl_xor(sum, off, 64);
    float lse = mx + __logf(sum);
    if (owner)
        *(float2*)(out + (size_t)d * CLS + 2 * c32) = make_float2(vx - lse, vy - lse);
}

extern "C" void kernel_launch(void* const* d_in, const int* in_sizes, int n_in,
                              void* d_out, int out_size, void* d_ws, size_t ws_size,
                              hipStream_t stream) {
    const float* x   = (const float*)d_in[0];
    const int*   ei  = (const int*)d_in[1];
    const float* W1  = (const float*)d_in[2];
    const float* aS1 = (const float*)d_in[3];
    const float* aD1 = (const float*)d_in[4];
    const float* b1  = (const float*)d_in[5];
    const float* W2  = (const float*)d_in[6];
    const float* aS2 = (const float*)d_in[7];
    const float* aD2 = (const float*)d_in[8];
    const float* b2  = (const float*)d_in[9];
    float* out = (float*)d_out;

    int n = in_sizes[0] / FIN;   // 100000
    int E = in_sizes[1] / 2;     // 1600000
    int En = E + n;

    // ws layout (~36 MB): h1b bf16 n*64 | h2b bf16 n*40 | alS1 f32 n*8 |
    // alD1 f32 n*8 | alS2 f32 n | alD2 f32 n | csr int En | rowstart int n+1 |
    // deg int n | bsum int 512
    char* wsb = (char*)d_ws;
    bf16*  h1b  = (bf16*)wsb;
    bf16*  h2b  = h1b + (size_t)n * C1;
    float* alS1 = (float*)(h2b + (size_t)n * CLS);
    float* alD1 = alS1 + (size_t)n * HEADS;
    float* alS2 = alD1 + (size_t)n * HEADS;
    float* alD2 = alS2 + n;
    int*   csr  = (int*)(alD2 + n);
    int*   rowstart = csr + En;
    int*   deg  = rowstart + n + 1;
    int*   bsum = deg + n;

    const int T = 256;
    int nb = (n + 255) / 256;                      // 391 (<=512)
    int nblocks = (n + 63) / 64;
    if (nblocks < 256) nblocks = 256;              // deg tail needs 256 blocks

    // ---- gemm1 (+ fused LDS-histogram degree count) ----
    (void)hipMemsetAsync(deg, 0, (size_t)n * sizeof(int), stream);
    gemm1_kernel<<<nblocks, T, 0, stream>>>(x, W1, aS1, aD1, h1b, alS1, alD1,
                                            n, ei, E, deg);

    // ---- CSR build (scan + scatter) ----
    k_scan1<<<nb, T, 0, stream>>>(deg, rowstart, bsum, n);
    k_scan2<<<1, 512, 0, stream>>>(bsum, nb);
    k_scan3<<<nb, T, 0, stream>>>(rowstart, bsum, n, En);
    int chunks = (En + 1023) / 1024;               // 4 edges/thread
    k_scatter<<<chunks * 8, T, 0, stream>>>(ei, E, En, n, rowstart, csr);

    // ---- layer 1 aggregate (+ fused gemm2), grid-stride ----
    k_agg1<<<2048, T, 0, stream>>>(csr, rowstart, deg, alS1, alD1, h1b, b1,
                                   W2, aS2, aD2, h2b, alS2, alD2, n);

    // ---- layer 2 ----
    k_agg2<<<(n + 3) / 4, T, 0, stream>>>(csr, rowstart, deg, alS2, alD2, h2b, b2, out, n);
}